// Round 2
// baseline (669.495 us; speedup 1.0000x reference)
//
#include <hip/hip_runtime.h>

// DistanceNetwork: out[b,n] = <support[n,b,:], targets[b,:]> * rsqrt(max(||support[n,b,:]||^2, EPS))
// support_set: [N=512, B=256, D=1024] f32, targets: [B=256, D=1024] f32, out: [B, N] f32.
// Memory-bound: stream 512 MiB of support once; targets (1 MiB) hits L2.

#define N_SUP 512
#define B_DIM 256
#define D_DIM 1024
#define EPS_CLIP 1e-10f

__global__ __launch_bounds__(256) void distnet_kernel(
    const float* __restrict__ support,
    const float* __restrict__ targets,
    float* __restrict__ out)
{
    const int lane = threadIdx.x & 63;
    const int wave_in_block = threadIdx.x >> 6;
    const int waves_per_grid = gridDim.x * 4;
    const int total_rows = N_SUP * B_DIM;

    for (int row = blockIdx.x * 4 + wave_in_block; row < total_rows; row += waves_per_grid) {
        const int n = row >> 8;            // row / B_DIM
        const int b = row & (B_DIM - 1);   // row % B_DIM

        const float4* sp = reinterpret_cast<const float4*>(support + (size_t)row * D_DIM);
        const float4* tp = reinterpret_cast<const float4*>(targets + (size_t)b * D_DIM);

        float dot = 0.0f;
        float ss  = 0.0f;
        #pragma unroll
        for (int i = 0; i < 4; ++i) {
            float4 s = sp[i * 64 + lane];
            float4 t = tp[i * 64 + lane];
            dot = fmaf(s.x, t.x, dot);
            dot = fmaf(s.y, t.y, dot);
            dot = fmaf(s.z, t.z, dot);
            dot = fmaf(s.w, t.w, dot);
            ss  = fmaf(s.x, s.x, ss);
            ss  = fmaf(s.y, s.y, ss);
            ss  = fmaf(s.z, s.z, ss);
            ss  = fmaf(s.w, s.w, ss);
        }

        // 64-lane butterfly reduction of both accumulators
        #pragma unroll
        for (int off = 32; off >= 1; off >>= 1) {
            dot += __shfl_xor(dot, off, 64);
            ss  += __shfl_xor(ss,  off, 64);
        }

        if (lane == 0) {
            float inv = 1.0f / sqrtf(fmaxf(ss, EPS_CLIP));
            out[(size_t)b * N_SUP + n] = dot * inv;
        }
    }
}

extern "C" void kernel_launch(void* const* d_in, const int* in_sizes, int n_in,
                              void* d_out, int out_size, void* d_ws, size_t ws_size,
                              hipStream_t stream) {
    const float* support = (const float*)d_in[0];
    const float* targets = (const float*)d_in[1];
    float* out = (float*)d_out;

    // 2048 blocks x 256 threads = 8192 waves; 131072 rows -> 16 rows/wave.
    distnet_kernel<<<2048, 256, 0, stream>>>(support, targets, out);
}

// Round 4
// 639.513 us; speedup vs baseline: 1.0469x; 1.0469x over previous
//
#include <hip/hip_runtime.h>

// DistanceNetwork: out[b,n] = <support[n,b,:], targets[b,:]> * rsqrt(max(||support[n,b,:]||^2, EPS))
// support_set: [N=512, B=256, D=1024] f32 (512 MiB, streamed once -> nontemporal),
// targets: [B=256, D=1024] f32 (1 MiB, reused N times -> cached path),
// out: [B, N] f32.
// Memory-bound: floor = 537 MB / 6.4 TB/s (measured achievable) ~ 84 us.

#define N_SUP 512
#define B_DIM 256
#define D_DIM 1024
#define EPS_CLIP 1e-10f

typedef float f32x4 __attribute__((ext_vector_type(4)));

__global__ __launch_bounds__(256) void distnet_kernel(
    const float* __restrict__ support,
    const float* __restrict__ targets,
    float* __restrict__ out)
{
    const int lane = threadIdx.x & 63;
    const int wave_in_block = threadIdx.x >> 6;
    const int waves_per_grid = gridDim.x * 4;
    const int total_rows = N_SUP * B_DIM;

    for (int row = blockIdx.x * 4 + wave_in_block; row < total_rows; row += waves_per_grid) {
        const int n = row >> 8;            // row / B_DIM
        const int b = row & (B_DIM - 1);   // row % B_DIM

        const f32x4* sp = reinterpret_cast<const f32x4*>(support + (size_t)row * D_DIM);
        const f32x4* tp = reinterpret_cast<const f32x4*>(targets + (size_t)b * D_DIM);

        // Issue all 8 loads up front for max MLP; support via nontemporal
        // (zero reuse -> don't evict the L2-resident targets).
        f32x4 s0 = __builtin_nontemporal_load(sp + 0 * 64 + lane);
        f32x4 s1 = __builtin_nontemporal_load(sp + 1 * 64 + lane);
        f32x4 s2 = __builtin_nontemporal_load(sp + 2 * 64 + lane);
        f32x4 s3 = __builtin_nontemporal_load(sp + 3 * 64 + lane);
        f32x4 t0 = tp[0 * 64 + lane];
        f32x4 t1 = tp[1 * 64 + lane];
        f32x4 t2 = tp[2 * 64 + lane];
        f32x4 t3 = tp[3 * 64 + lane];

        float dot = 0.0f, ss = 0.0f;
        #pragma unroll
        for (int j = 0; j < 4; ++j) {
            dot = fmaf(s0[j], t0[j], dot);  ss = fmaf(s0[j], s0[j], ss);
        }
        #pragma unroll
        for (int j = 0; j < 4; ++j) {
            dot = fmaf(s1[j], t1[j], dot);  ss = fmaf(s1[j], s1[j], ss);
        }
        #pragma unroll
        for (int j = 0; j < 4; ++j) {
            dot = fmaf(s2[j], t2[j], dot);  ss = fmaf(s2[j], s2[j], ss);
        }
        #pragma unroll
        for (int j = 0; j < 4; ++j) {
            dot = fmaf(s3[j], t3[j], dot);  ss = fmaf(s3[j], s3[j], ss);
        }

        // 64-lane butterfly reduction of both accumulators
        #pragma unroll
        for (int off = 32; off >= 1; off >>= 1) {
            dot += __shfl_xor(dot, off, 64);
            ss  += __shfl_xor(ss,  off, 64);
        }

        if (lane == 0) {
            float inv = 1.0f / sqrtf(fmaxf(ss, EPS_CLIP));
            out[(size_t)b * N_SUP + n] = dot * inv;
        }
    }
}

extern "C" void kernel_launch(void* const* d_in, const int* in_sizes, int n_in,
                              void* d_out, int out_size, void* d_ws, size_t ws_size,
                              hipStream_t stream) {
    const float* support = (const float*)d_in[0];
    const float* targets = (const float*)d_in[1];
    float* out = (float*)d_out;

    // 2048 blocks x 256 threads = 8192 waves = 8 blocks/CU; 131072 rows -> 16 rows/wave.
    distnet_kernel<<<2048, 256, 0, stream>>>(support, targets, out);
}